// Round 18
// baseline (147.020 us; speedup 1.0000x reference)
//
#include <hip/hip_runtime.h>
#include <cstddef>

// TAGConv K=2: out = concat(x, m1, m2) @ W^T + b
// R18: wave-per-node gathers -- 64 lanes = 4 edge-groups x 16 slices, 16
// edges in flight, wave-uniform loop (kills the max-of-4-nodes divergence of
// the 16-lane layout), col reads broadcast, 2x shfl_xor group reduce.
// zero folded into convpack (6 -> 5 launches). CSR build + fused
// gather2+gemm structure from R17 (137.3us) otherwise unchanged.

#define DFEAT 128
#define SUBSHIFT 8                 // 256 nodes per subrange
#define MAXSUB 256                 // >= ceil(50000/256)=196
#define EPB 2048                   // edges per partitionA block (8/thread)
#define CAP 16384                  // staging slots per subrange (worst ~10.4k)

typedef __attribute__((ext_vector_type(8))) short short8v;  // 8 bf16 = 4 VGPR
typedef __attribute__((ext_vector_type(4))) float f32x4;
typedef __attribute__((ext_vector_type(4))) unsigned int uint4v;

__device__ inline unsigned short f2bf(float f) {   // RNE f32 -> bf16
    unsigned int u;
    __builtin_memcpy(&u, &f, 4);
    unsigned int r = u + 0x7FFFu + ((u >> 16) & 1u);
    return (unsigned short)(r >> 16);
}
__device__ inline float bf2f(unsigned short h) {
    unsigned int u = ((unsigned int)h) << 16;
    float f;
    __builtin_memcpy(&f, &u, 4);
    return f;
}

// ---- merged: zero subFill/subReal + conv (x -> xb) + pack (W -> Wpk) --------
__global__ void convpack_kernel(const float* __restrict__ x,
                                unsigned short* __restrict__ xb, int total8,
                                const float* __restrict__ W,
                                unsigned short* __restrict__ Wpk,
                                int* __restrict__ zeroPtr) {
    const int i = blockIdx.x * blockDim.x + threadIdx.x;
    if (i < 2 * MAXSUB) zeroPtr[i] = 0;
    if (i < total8) {
        const float* s = x + (size_t)i * 8;
        const float4 a = *reinterpret_cast<const float4*>(s);
        const float4 b = *reinterpret_cast<const float4*>(s + 4);
        uint4v w;
        w.x = (unsigned)f2bf(a.x) | ((unsigned)f2bf(a.y) << 16);
        w.y = (unsigned)f2bf(a.z) | ((unsigned)f2bf(a.w) << 16);
        w.z = (unsigned)f2bf(b.x) | ((unsigned)f2bf(b.y) << 16);
        w.w = (unsigned)f2bf(b.z) | ((unsigned)f2bf(b.w) << 16);
        *reinterpret_cast<uint4v*>(xb + (size_t)i * 8) = w;
        return;
    }
    const int idx = i - total8;                    // 12*8*64 = 6144 pack items
    if (idx >= 6144) return;
    const int lane = idx & 63;
    const int nt = (idx >> 6) & 7;
    const int ks = idx >> 9;
    const int col = nt * 16 + (lane & 15);
    const int k = ks * 32 + (lane >> 4) * 8;
    const float* wp = W + (size_t)col * 384 + k;
    uint4v w;
    w.x = (unsigned)f2bf(wp[0]) | ((unsigned)f2bf(wp[1]) << 16);
    w.y = (unsigned)f2bf(wp[2]) | ((unsigned)f2bf(wp[3]) << 16);
    w.z = (unsigned)f2bf(wp[4]) | ((unsigned)f2bf(wp[5]) << 16);
    w.w = (unsigned)f2bf(wp[6]) | ((unsigned)f2bf(wp[7]) << 16);
    *reinterpret_cast<uint4v*>(Wpk + (size_t)idx * 8) = w;
}

// ---- phase A: bucket edges into line-aligned chunks of fixed segments -------
__global__ __launch_bounds__(256) void partitionA_kernel(
    const int* __restrict__ src, const int* __restrict__ dst,
    int* __restrict__ subFill, int* __restrict__ subReal,
    uint2* __restrict__ staging, int E, int nsub) {
    __shared__ int cnt[MAXSUB];
    __shared__ int base[MAXSUB];
    const int t = threadIdx.x;
    for (int i = t; i < nsub; i += 256) cnt[i] = 0;
    __syncthreads();
    const int e0 = blockIdx.x * EPB;
    int d[8], s[8], b[8], rk[8];
#pragma unroll
    for (int j = 0; j < 8; ++j) {
        const int e = e0 + j * 256 + t;
        if (e < E) {
            d[j] = __builtin_nontemporal_load(dst + e);
            s[j] = __builtin_nontemporal_load(src + e);
            b[j] = d[j] >> SUBSHIFT;
            rk[j] = atomicAdd(&cnt[b[j]], 1);
        } else {
            d[j] = -1; s[j] = 0; b[j] = 0; rk[j] = 0;
        }
    }
    __syncthreads();
    for (int i = t; i < nsub; i += 256) {
        const int c = cnt[i];
        if (c > 0) {
            const int padded = (c + 15) & ~15;
            int bse = atomicAdd(&subFill[i], padded);
            if (bse + padded > CAP) bse = CAP - padded;   // safety clamp
            base[i] = bse;
            atomicAdd(&subReal[i], c);
        }
    }
    __syncthreads();
#pragma unroll
    for (int j = 0; j < 8; ++j)
        if (d[j] >= 0)
            staging[(size_t)b[j] * CAP + base[b[j]] + rk[j]] =
                make_uint2((unsigned)d[j], (unsigned)s[j]);
    for (int i = t; i < nsub; i += 256) {
        const int c = cnt[i];
        if (c > 0) {
            const int padded = (c + 15) & ~15;
            for (int k = c; k < padded; ++k)
                staging[(size_t)i * CAP + base[i] + k] = make_uint2(0xFFFFFFFFu, 0u);
        }
    }
}

// ---- phase B: in-block subReal scan + deg count + local scan + scatter ------
__global__ __launch_bounds__(256) void partitionB_kernel(
    const uint2* __restrict__ staging, const int* __restrict__ subFill,
    const int* __restrict__ subReal, int* __restrict__ rowptr,
    float* __restrict__ inv, int* __restrict__ col, int N, int E, int nsub) {
    __shared__ int ss[256];
    __shared__ int cnt[1 << SUBSHIFT];
    __shared__ int loc[1 << SUBSHIFT];
    __shared__ int cur[1 << SUBSHIFT];
    const int b = blockIdx.x;
    const int n0 = b << SUBSHIFT;
    const int t = threadIdx.x;
    ss[t] = (t < nsub) ? subReal[t] : 0;
    cnt[t] = 0;
    __syncthreads();
#pragma unroll
    for (int off = 1; off < 256; off <<= 1) {
        int x = (t >= off) ? ss[t - off] : 0;
        __syncthreads();
        ss[t] += x;
        __syncthreads();
    }
    const int myBase = (b > 0) ? ss[b - 1] : 0;
    const int fill = min(subFill[b], CAP);
    const uint2* seg = staging + (size_t)b * CAP;
    for (int i = t; i < fill; i += 256) {
        const unsigned dd = seg[i].x;
        if (dd != 0xFFFFFFFFu) atomicAdd(&cnt[dd - (unsigned)n0], 1);
    }
    __syncthreads();
    const int v = cnt[t];
    loc[t] = v;
    __syncthreads();
#pragma unroll
    for (int off = 1; off < 256; off <<= 1) {
        int x = (t >= off) ? loc[t - off] : 0;
        __syncthreads();
        loc[t] += x;
        __syncthreads();
    }
    const int gpos = myBase + loc[t] - v;
    const int n = n0 + t;
    if (n < N) {
        rowptr[n] = gpos;
        inv[n] = 1.0f / (float)max(v, 1);
    }
    cur[t] = gpos;
    __syncthreads();
    for (int i = t; i < fill; i += 256) {
        const uint2 pr = seg[i];
        if (pr.x != 0xFFFFFFFFu) {
            const int pos = atomicAdd(&cur[(int)pr.x - n0], 1);
            col[pos] = (int)pr.y;
        }
    }
    if (b == 0 && t == 0) rowptr[N] = E;
}

// ---- wave-per-node gather body (shared by standalone + fused) ---------------
// 64 lanes = 4 edge-groups (g) x 16 slices (s). 16 edges in flight.
// Returns per-lane partial acc[8]; caller reduces across groups.
__device__ inline void gather_wave_acc(const unsigned short* __restrict__ feat,
                                       const int* __restrict__ col,
                                       int beg, int end, int g, int s,
                                       float acc[8]) {
#pragma unroll
    for (int j = 0; j < 8; ++j) acc[j] = 0.0f;
    int e = beg;
    for (; e + 15 < end; e += 16) {
        const int i0 = col[e + g];
        const int i1 = col[e + 4 + g];
        const int i2 = col[e + 8 + g];
        const int i3 = col[e + 12 + g];
        const short8v v0 = *reinterpret_cast<const short8v*>(feat + (size_t)i0 * DFEAT + s * 8);
        const short8v v1 = *reinterpret_cast<const short8v*>(feat + (size_t)i1 * DFEAT + s * 8);
        const short8v v2 = *reinterpret_cast<const short8v*>(feat + (size_t)i2 * DFEAT + s * 8);
        const short8v v3 = *reinterpret_cast<const short8v*>(feat + (size_t)i3 * DFEAT + s * 8);
#pragma unroll
        for (int j = 0; j < 8; ++j)
            acc[j] += (bf2f((unsigned short)v0[j]) + bf2f((unsigned short)v1[j])) +
                      (bf2f((unsigned short)v2[j]) + bf2f((unsigned short)v3[j]));
    }
    for (; e + 3 < end; e += 4) {
        const int i0 = col[e + g];
        const short8v v0 = *reinterpret_cast<const short8v*>(feat + (size_t)i0 * DFEAT + s * 8);
#pragma unroll
        for (int j = 0; j < 8; ++j) acc[j] += bf2f((unsigned short)v0[j]);
    }
    if (e + g < end) {
        const int i0 = col[e + g];
        const short8v v0 = *reinterpret_cast<const short8v*>(feat + (size_t)i0 * DFEAT + s * 8);
#pragma unroll
        for (int j = 0; j < 8; ++j) acc[j] += bf2f((unsigned short)v0[j]);
    }
}

// ---- standalone gather (pass 1): one wave per node --------------------------
__global__ __launch_bounds__(256) void gather_wave_kernel(
    const unsigned short* __restrict__ feat, const int* __restrict__ rowptr,
    const int* __restrict__ col, const float* __restrict__ inv,
    unsigned short* __restrict__ outb, int N) {
    const int wv = threadIdx.x >> 6;
    const int lane = threadIdx.x & 63;
    const int g = lane >> 4;
    const int s = lane & 15;
    const int n = blockIdx.x * 4 + wv;
    if (n >= N) return;
    float acc[8];
    gather_wave_acc(feat, col, rowptr[n], rowptr[n + 1], g, s, acc);
#pragma unroll
    for (int j = 0; j < 8; ++j) {
        acc[j] += __shfl_xor(acc[j], 16, 64);
        acc[j] += __shfl_xor(acc[j], 32, 64);
    }
    if (g == 0) {
        const float sc = inv[n];
        uint4v w;
        w.x = (unsigned)f2bf(acc[0] * sc) | ((unsigned)f2bf(acc[1] * sc) << 16);
        w.y = (unsigned)f2bf(acc[2] * sc) | ((unsigned)f2bf(acc[3] * sc) << 16);
        w.z = (unsigned)f2bf(acc[4] * sc) | ((unsigned)f2bf(acc[5] * sc) << 16);
        w.w = (unsigned)f2bf(acc[6] * sc) | ((unsigned)f2bf(acc[7] * sc) << 16);
        *reinterpret_cast<uint4v*>(outb + (size_t)n * DFEAT + s * 8) = w;
    }
}

// ---- fused gather2 + MFMA GEMM ----------------------------------------------
// Gather phase: each of 4 waves computes 16 nodes (one wave-per-node at a
// time) into LDS m2s. GEMM phase: A-frags x/m1 from global, m2 from LDS.
#define M2PAD 132
__global__ __launch_bounds__(256) void gather_gemm_kernel(
    const unsigned short* __restrict__ xb, const unsigned short* __restrict__ m1b,
    const unsigned short* __restrict__ Wpk, const int* __restrict__ rowptr,
    const int* __restrict__ col, const float* __restrict__ inv,
    const float* __restrict__ bias, float* __restrict__ out, int N) {
    __shared__ unsigned short m2s[64][M2PAD];
    const int t = threadIdx.x;
    const int nodeBase = blockIdx.x * 64;
    const int w = t >> 6;
    const int lane = t & 63;
    const int g = lane >> 4;
    const int s = lane & 15;

    for (int r = 0; r < 16; ++r) {
        const int ln = w * 16 + r;
        const int n = nodeBase + ln;
        float acc[8];
        if (n < N) {
            gather_wave_acc(m1b, col, rowptr[n], rowptr[n + 1], g, s, acc);
#pragma unroll
            for (int j = 0; j < 8; ++j) {
                acc[j] += __shfl_xor(acc[j], 16, 64);
                acc[j] += __shfl_xor(acc[j], 32, 64);
            }
            if (g == 0) {
                const float sc = inv[n];
                unsigned short* dstp = &m2s[ln][s * 8];
#pragma unroll
                for (int j = 0; j < 8; ++j) dstp[j] = f2bf(acc[j] * sc);
            }
        } else if (g == 0) {
            unsigned short* dstp = &m2s[ln][s * 8];
#pragma unroll
            for (int j = 0; j < 8; ++j) dstp[j] = 0;
        }
    }
    __syncthreads();

    // ---- gemm phase ----
    const int lr = lane & 15;
    const int kg = lane >> 4;
    const int rowBase = nodeBase + w * 16;
    int arow = rowBase + lr;
    if (arow >= N) arow = N - 1;      // clamp (duplicate read, store is guarded)

    const short8v* Wv = reinterpret_cast<const short8v*>(Wpk);

    f32x4 acc[8];
#pragma unroll
    for (int nt = 0; nt < 8; ++nt) acc[nt] = (f32x4){0.f, 0.f, 0.f, 0.f};

#pragma unroll
    for (int ks = 0; ks < 12; ++ks) {
        const int q = ks & 3;
        short8v a;
        if (ks < 8) {
            const unsigned short* feat = (ks < 4) ? xb : m1b;
            a = *reinterpret_cast<const short8v*>(
                feat + (size_t)arow * DFEAT + q * 32 + kg * 8);
        } else {
            a = *reinterpret_cast<const short8v*>(&m2s[w * 16 + lr][q * 32 + kg * 8]);
        }
        short8v bfrag[8];
#pragma unroll
        for (int nt = 0; nt < 8; ++nt)
            bfrag[nt] = Wv[(ks * 8 + nt) * 64 + lane];
#pragma unroll
        for (int nt = 0; nt < 8; ++nt)
            acc[nt] = __builtin_amdgcn_mfma_f32_16x16x32_bf16(a, bfrag[nt], acc[nt], 0, 0, 0);
    }

#pragma unroll
    for (int nt = 0; nt < 8; ++nt) {
        const int c = nt * 16 + lr;
        const float bv = bias[c];
#pragma unroll
        for (int r = 0; r < 4; ++r) {
            const int node = rowBase + kg * 4 + r;
            if (node < N) out[(size_t)node * DFEAT + c] = acc[nt][r] + bv;
        }
    }
}

extern "C" void kernel_launch(void* const* d_in, const int* in_sizes, int n_in,
                              void* d_out, int out_size, void* d_ws, size_t ws_size,
                              hipStream_t stream) {
    (void)n_in; (void)out_size; (void)ws_size;
    const float* x  = (const float*)d_in[0];
    const int*   ei = (const int*)d_in[1];
    const float* W  = (const float*)d_in[2];
    const float* b  = (const float*)d_in[3];
    float* out = (float*)d_out;

    const int N = in_sizes[0] / DFEAT;
    const int E = in_sizes[1] / 2;
    const int* src = ei;
    const int* dst = ei + E;
    const int nsub = (N + (1 << SUBSHIFT) - 1) >> SUBSHIFT;   // 196 for N=50000

    auto up = [](size_t v) { return (v + 255) & ~(size_t)255; };
    char* p = (char*)d_ws;
    int*   subFill   = (int*)p;            p += up((size_t)MAXSUB * 4 * 2); // +subReal
    int*   subReal   = subFill + MAXSUB;
    int*   rowptr    = (int*)p;            p += up(((size_t)N + 1) * 4);
    uint2* staging   = (uint2*)p;          p += up((size_t)MAXSUB * CAP * 8);
    int*   col       = (int*)p;            p += up((size_t)E * 4);
    float* inv       = (float*)p;          p += up((size_t)N * 4);
    unsigned short* xb  = (unsigned short*)p;  p += up((size_t)N * DFEAT * 2);
    unsigned short* m1b = (unsigned short*)p;  p += up((size_t)N * DFEAT * 2);
    unsigned short* Wpk = (unsigned short*)p;  p += up((size_t)6144 * 8 * 2);

    const int x8 = N * DFEAT / 8;
    convpack_kernel<<<(x8 + 6144 + 255) / 256, 256, 0, stream>>>(x, xb, x8, W, Wpk, subFill);

    partitionA_kernel<<<(E + EPB - 1) / EPB, 256, 0, stream>>>(src, dst, subFill, subReal,
                                                               staging, E, nsub);
    partitionB_kernel<<<nsub, 256, 0, stream>>>(staging, subFill, subReal,
                                                rowptr, inv, col, N, E, nsub);

    gather_wave_kernel<<<(N + 3) / 4, 256, 0, stream>>>(xb, rowptr, col, inv, m1b, N);

    gather_gemm_kernel<<<(N + 63) / 64, 256, 0, stream>>>(xb, m1b, Wpk, rowptr, col,
                                                          inv, b, out, N);
}

// Round 19
// 123.967 us; speedup vs baseline: 1.1860x; 1.1860x over previous
//
#include <hip/hip_runtime.h>
#include <cstddef>

// TAGConv K=2: out = concat(x, m1, m2) @ W^T + b
// R19: revert R18's wave-per-node gather (regressed: serialized per-wave
// rounds + reduce chains). R17 structure, but fused gather2+gemm tile
// shrunk 64 -> 32 nodes to double occupancy (782 -> 1563 blocks, ~6/CU):
// gather = 2 rounds of 16-lane-per-node; gemm = 4 waves x (16 rows x 64
// cols). 5 launches (zero folded into convpack).

#define DFEAT 128
#define SUBSHIFT 8                 // 256 nodes per subrange
#define MAXSUB 256                 // >= ceil(50000/256)=196
#define EPB 2048                   // edges per partitionA block (8/thread)
#define CAP 16384                  // staging slots per subrange (worst ~10.4k)

typedef __attribute__((ext_vector_type(8))) short short8v;  // 8 bf16 = 4 VGPR
typedef __attribute__((ext_vector_type(4))) float f32x4;
typedef __attribute__((ext_vector_type(4))) unsigned int uint4v;

__device__ inline unsigned short f2bf(float f) {   // RNE f32 -> bf16
    unsigned int u;
    __builtin_memcpy(&u, &f, 4);
    unsigned int r = u + 0x7FFFu + ((u >> 16) & 1u);
    return (unsigned short)(r >> 16);
}
__device__ inline float bf2f(unsigned short h) {
    unsigned int u = ((unsigned int)h) << 16;
    float f;
    __builtin_memcpy(&f, &u, 4);
    return f;
}

// ---- merged: zero subFill/subReal + conv (x -> xb) + pack (W -> Wpk) --------
__global__ void convpack_kernel(const float* __restrict__ x,
                                unsigned short* __restrict__ xb, int total8,
                                const float* __restrict__ W,
                                unsigned short* __restrict__ Wpk,
                                int* __restrict__ zeroPtr) {
    const int i = blockIdx.x * blockDim.x + threadIdx.x;
    if (i < 2 * MAXSUB) zeroPtr[i] = 0;
    if (i < total8) {
        const float* s = x + (size_t)i * 8;
        const float4 a = *reinterpret_cast<const float4*>(s);
        const float4 b = *reinterpret_cast<const float4*>(s + 4);
        uint4v w;
        w.x = (unsigned)f2bf(a.x) | ((unsigned)f2bf(a.y) << 16);
        w.y = (unsigned)f2bf(a.z) | ((unsigned)f2bf(a.w) << 16);
        w.z = (unsigned)f2bf(b.x) | ((unsigned)f2bf(b.y) << 16);
        w.w = (unsigned)f2bf(b.z) | ((unsigned)f2bf(b.w) << 16);
        *reinterpret_cast<uint4v*>(xb + (size_t)i * 8) = w;
        return;
    }
    const int idx = i - total8;                    // 12*8*64 = 6144 pack items
    if (idx >= 6144) return;
    const int lane = idx & 63;
    const int nt = (idx >> 6) & 7;
    const int ks = idx >> 9;
    const int col = nt * 16 + (lane & 15);
    const int k = ks * 32 + (lane >> 4) * 8;
    const float* wp = W + (size_t)col * 384 + k;
    uint4v w;
    w.x = (unsigned)f2bf(wp[0]) | ((unsigned)f2bf(wp[1]) << 16);
    w.y = (unsigned)f2bf(wp[2]) | ((unsigned)f2bf(wp[3]) << 16);
    w.z = (unsigned)f2bf(wp[4]) | ((unsigned)f2bf(wp[5]) << 16);
    w.w = (unsigned)f2bf(wp[6]) | ((unsigned)f2bf(wp[7]) << 16);
    *reinterpret_cast<uint4v*>(Wpk + (size_t)idx * 8) = w;
}

// ---- phase A: bucket edges into line-aligned chunks of fixed segments -------
__global__ __launch_bounds__(256) void partitionA_kernel(
    const int* __restrict__ src, const int* __restrict__ dst,
    int* __restrict__ subFill, int* __restrict__ subReal,
    uint2* __restrict__ staging, int E, int nsub) {
    __shared__ int cnt[MAXSUB];
    __shared__ int base[MAXSUB];
    const int t = threadIdx.x;
    for (int i = t; i < nsub; i += 256) cnt[i] = 0;
    __syncthreads();
    const int e0 = blockIdx.x * EPB;
    int d[8], s[8], b[8], rk[8];
#pragma unroll
    for (int j = 0; j < 8; ++j) {
        const int e = e0 + j * 256 + t;
        if (e < E) {
            d[j] = __builtin_nontemporal_load(dst + e);
            s[j] = __builtin_nontemporal_load(src + e);
            b[j] = d[j] >> SUBSHIFT;
            rk[j] = atomicAdd(&cnt[b[j]], 1);
        } else {
            d[j] = -1; s[j] = 0; b[j] = 0; rk[j] = 0;
        }
    }
    __syncthreads();
    for (int i = t; i < nsub; i += 256) {
        const int c = cnt[i];
        if (c > 0) {
            const int padded = (c + 15) & ~15;
            int bse = atomicAdd(&subFill[i], padded);
            if (bse + padded > CAP) bse = CAP - padded;   // safety clamp
            base[i] = bse;
            atomicAdd(&subReal[i], c);
        }
    }
    __syncthreads();
#pragma unroll
    for (int j = 0; j < 8; ++j)
        if (d[j] >= 0)
            staging[(size_t)b[j] * CAP + base[b[j]] + rk[j]] =
                make_uint2((unsigned)d[j], (unsigned)s[j]);
    for (int i = t; i < nsub; i += 256) {
        const int c = cnt[i];
        if (c > 0) {
            const int padded = (c + 15) & ~15;
            for (int k = c; k < padded; ++k)
                staging[(size_t)i * CAP + base[i] + k] = make_uint2(0xFFFFFFFFu, 0u);
        }
    }
}

// ---- phase B: in-block subReal scan + deg count + local scan + scatter ------
__global__ __launch_bounds__(256) void partitionB_kernel(
    const uint2* __restrict__ staging, const int* __restrict__ subFill,
    const int* __restrict__ subReal, int* __restrict__ rowptr,
    float* __restrict__ inv, int* __restrict__ col, int N, int E, int nsub) {
    __shared__ int ss[256];
    __shared__ int cnt[1 << SUBSHIFT];
    __shared__ int loc[1 << SUBSHIFT];
    __shared__ int cur[1 << SUBSHIFT];
    const int b = blockIdx.x;
    const int n0 = b << SUBSHIFT;
    const int t = threadIdx.x;
    ss[t] = (t < nsub) ? subReal[t] : 0;
    cnt[t] = 0;
    __syncthreads();
#pragma unroll
    for (int off = 1; off < 256; off <<= 1) {
        int x = (t >= off) ? ss[t - off] : 0;
        __syncthreads();
        ss[t] += x;
        __syncthreads();
    }
    const int myBase = (b > 0) ? ss[b - 1] : 0;
    const int fill = min(subFill[b], CAP);
    const uint2* seg = staging + (size_t)b * CAP;
    for (int i = t; i < fill; i += 256) {
        const unsigned dd = seg[i].x;
        if (dd != 0xFFFFFFFFu) atomicAdd(&cnt[dd - (unsigned)n0], 1);
    }
    __syncthreads();
    const int v = cnt[t];
    loc[t] = v;
    __syncthreads();
#pragma unroll
    for (int off = 1; off < 256; off <<= 1) {
        int x = (t >= off) ? loc[t - off] : 0;
        __syncthreads();
        loc[t] += x;
        __syncthreads();
    }
    const int gpos = myBase + loc[t] - v;
    const int n = n0 + t;
    if (n < N) {
        rowptr[n] = gpos;
        inv[n] = 1.0f / (float)max(v, 1);
    }
    cur[t] = gpos;
    __syncthreads();
    for (int i = t; i < fill; i += 256) {
        const uint2 pr = seg[i];
        if (pr.x != 0xFFFFFFFFu) {
            const int pos = atomicAdd(&cur[(int)pr.x - n0], 1);
            col[pos] = (int)pr.y;
        }
    }
    if (b == 0 && t == 0) rowptr[N] = E;
}

// ---- standalone bf16 gather (pass 1): 16 lanes/node, 4 edges in flight ------
__global__ __launch_bounds__(256) void gather_bf16_kernel(
    const unsigned short* __restrict__ feat, const int* __restrict__ rowptr,
    const int* __restrict__ col, const float* __restrict__ inv,
    unsigned short* __restrict__ outb, int N) {
    const int n = blockIdx.x * 16 + (threadIdx.x >> 4);
    const int lane = threadIdx.x & 15;
    if (n >= N) return;
    const int beg = rowptr[n];
    const int end = rowptr[n + 1];
    float acc[8];
#pragma unroll
    for (int j = 0; j < 8; ++j) acc[j] = 0.0f;
    int e = beg;
    for (; e + 3 < end; e += 4) {
        const int s0 = col[e];
        const int s1 = col[e + 1];
        const int s2 = col[e + 2];
        const int s3 = col[e + 3];
        const short8v v0 = *reinterpret_cast<const short8v*>(feat + (size_t)s0 * DFEAT + lane * 8);
        const short8v v1 = *reinterpret_cast<const short8v*>(feat + (size_t)s1 * DFEAT + lane * 8);
        const short8v v2 = *reinterpret_cast<const short8v*>(feat + (size_t)s2 * DFEAT + lane * 8);
        const short8v v3 = *reinterpret_cast<const short8v*>(feat + (size_t)s3 * DFEAT + lane * 8);
#pragma unroll
        for (int j = 0; j < 8; ++j)
            acc[j] += (bf2f((unsigned short)v0[j]) + bf2f((unsigned short)v1[j])) +
                      (bf2f((unsigned short)v2[j]) + bf2f((unsigned short)v3[j]));
    }
    for (; e < end; ++e) {
        const int s0 = col[e];
        const short8v v0 = *reinterpret_cast<const short8v*>(feat + (size_t)s0 * DFEAT + lane * 8);
#pragma unroll
        for (int j = 0; j < 8; ++j) acc[j] += bf2f((unsigned short)v0[j]);
    }
    const float sc = inv[n];
    uint4v w;
    w.x = (unsigned)f2bf(acc[0] * sc) | ((unsigned)f2bf(acc[1] * sc) << 16);
    w.y = (unsigned)f2bf(acc[2] * sc) | ((unsigned)f2bf(acc[3] * sc) << 16);
    w.z = (unsigned)f2bf(acc[4] * sc) | ((unsigned)f2bf(acc[5] * sc) << 16);
    w.w = (unsigned)f2bf(acc[6] * sc) | ((unsigned)f2bf(acc[7] * sc) << 16);
    *reinterpret_cast<uint4v*>(outb + (size_t)n * DFEAT + lane * 8) = w;
}

// ---- fused gather2 + MFMA GEMM, 32-node tile --------------------------------
// Gather: 2 rounds x 16 nodes x 16 lanes into LDS m2s (R17 structure).
// GEMM: 4 waves; wave w owns rows (w>>1)*16..+16, cols (w&1)*64..+64.
#define M2PAD 132
__global__ __launch_bounds__(256) void gather_gemm_kernel(
    const unsigned short* __restrict__ xb, const unsigned short* __restrict__ m1b,
    const unsigned short* __restrict__ Wpk, const int* __restrict__ rowptr,
    const int* __restrict__ col, const float* __restrict__ inv,
    const float* __restrict__ bias, float* __restrict__ out, int N) {
    __shared__ unsigned short m2s[32][M2PAD];
    const int t = threadIdx.x;
    const int nodeBase = blockIdx.x * 32;
    const int lane16 = t & 15;

    // ---- gather phase: 2 rounds x 16 nodes, 16 lanes (16B) per node ----
    for (int r = 0; r < 2; ++r) {
        const int ln = r * 16 + (t >> 4);
        const int n = nodeBase + ln;
        float acc[8];
#pragma unroll
        for (int j = 0; j < 8; ++j) acc[j] = 0.0f;
        float sc = 0.0f;
        if (n < N) {
            const int beg = rowptr[n];
            const int end = rowptr[n + 1];
            int e = beg;
            for (; e + 3 < end; e += 4) {
                const int s0 = col[e];
                const int s1 = col[e + 1];
                const int s2 = col[e + 2];
                const int s3 = col[e + 3];
                const short8v v0 = *reinterpret_cast<const short8v*>(m1b + (size_t)s0 * DFEAT + lane16 * 8);
                const short8v v1 = *reinterpret_cast<const short8v*>(m1b + (size_t)s1 * DFEAT + lane16 * 8);
                const short8v v2 = *reinterpret_cast<const short8v*>(m1b + (size_t)s2 * DFEAT + lane16 * 8);
                const short8v v3 = *reinterpret_cast<const short8v*>(m1b + (size_t)s3 * DFEAT + lane16 * 8);
#pragma unroll
                for (int j = 0; j < 8; ++j)
                    acc[j] += (bf2f((unsigned short)v0[j]) + bf2f((unsigned short)v1[j])) +
                              (bf2f((unsigned short)v2[j]) + bf2f((unsigned short)v3[j]));
            }
            for (; e < end; ++e) {
                const int s0 = col[e];
                const short8v v0 = *reinterpret_cast<const short8v*>(m1b + (size_t)s0 * DFEAT + lane16 * 8);
#pragma unroll
                for (int j = 0; j < 8; ++j) acc[j] += bf2f((unsigned short)v0[j]);
            }
            sc = inv[n];
        }
        unsigned short* dstp = &m2s[ln][lane16 * 8];
#pragma unroll
        for (int j = 0; j < 8; ++j) dstp[j] = f2bf(acc[j] * sc);
    }
    __syncthreads();

    // ---- gemm phase: wave w -> rows (w>>1)*16, cols (w&1)*64 ----
    const int w = t >> 6;
    const int l = t & 63;
    const int lr = l & 15;
    const int kg = l >> 4;
    const int stripe = w >> 1;
    const int colHalf = w & 1;
    const int rowBase = nodeBase + stripe * 16;
    int arow = rowBase + lr;
    if (arow >= N) arow = N - 1;      // clamp (duplicate read, store is guarded)

    const short8v* Wv = reinterpret_cast<const short8v*>(Wpk);

    f32x4 acc[4];
#pragma unroll
    for (int nt = 0; nt < 4; ++nt) acc[nt] = (f32x4){0.f, 0.f, 0.f, 0.f};

#pragma unroll
    for (int ks = 0; ks < 12; ++ks) {
        const int q = ks & 3;
        short8v a;
        if (ks < 8) {
            const unsigned short* feat = (ks < 4) ? xb : m1b;
            a = *reinterpret_cast<const short8v*>(
                feat + (size_t)arow * DFEAT + q * 32 + kg * 8);
        } else {
            a = *reinterpret_cast<const short8v*>(&m2s[stripe * 16 + lr][q * 32 + kg * 8]);
        }
        short8v bfrag[4];
#pragma unroll
        for (int nt = 0; nt < 4; ++nt)
            bfrag[nt] = Wv[(ks * 8 + colHalf * 4 + nt) * 64 + l];
#pragma unroll
        for (int nt = 0; nt < 4; ++nt)
            acc[nt] = __builtin_amdgcn_mfma_f32_16x16x32_bf16(a, bfrag[nt], acc[nt], 0, 0, 0);
    }

#pragma unroll
    for (int nt = 0; nt < 4; ++nt) {
        const int c = (colHalf * 4 + nt) * 16 + lr;
        const float bv = bias[c];
#pragma unroll
        for (int r = 0; r < 4; ++r) {
            const int node = rowBase + kg * 4 + r;
            if (node < N) out[(size_t)node * DFEAT + c] = acc[nt][r] + bv;
        }
    }
}

extern "C" void kernel_launch(void* const* d_in, const int* in_sizes, int n_in,
                              void* d_out, int out_size, void* d_ws, size_t ws_size,
                              hipStream_t stream) {
    (void)n_in; (void)out_size; (void)ws_size;
    const float* x  = (const float*)d_in[0];
    const int*   ei = (const int*)d_in[1];
    const float* W  = (const float*)d_in[2];
    const float* b  = (const float*)d_in[3];
    float* out = (float*)d_out;

    const int N = in_sizes[0] / DFEAT;
    const int E = in_sizes[1] / 2;
    const int* src = ei;
    const int* dst = ei + E;
    const int nsub = (N + (1 << SUBSHIFT) - 1) >> SUBSHIFT;   // 196 for N=50000

    auto up = [](size_t v) { return (v + 255) & ~(size_t)255; };
    char* p = (char*)d_ws;
    int*   subFill   = (int*)p;            p += up((size_t)MAXSUB * 4 * 2); // +subReal
    int*   subReal   = subFill + MAXSUB;
    int*   rowptr    = (int*)p;            p += up(((size_t)N + 1) * 4);
    uint2* staging   = (uint2*)p;          p += up((size_t)MAXSUB * CAP * 8);
    int*   col       = (int*)p;            p += up((size_t)E * 4);
    float* inv       = (float*)p;          p += up((size_t)N * 4);
    unsigned short* xb  = (unsigned short*)p;  p += up((size_t)N * DFEAT * 2);
    unsigned short* m1b = (unsigned short*)p;  p += up((size_t)N * DFEAT * 2);
    unsigned short* Wpk = (unsigned short*)p;  p += up((size_t)6144 * 8 * 2);

    const int x8 = N * DFEAT / 8;
    convpack_kernel<<<(x8 + 6144 + 255) / 256, 256, 0, stream>>>(x, xb, x8, W, Wpk, subFill);

    partitionA_kernel<<<(E + EPB - 1) / EPB, 256, 0, stream>>>(src, dst, subFill, subReal,
                                                               staging, E, nsub);
    partitionB_kernel<<<nsub, 256, 0, stream>>>(staging, subFill, subReal,
                                                rowptr, inv, col, N, E, nsub);

    const int gatherBlocks = (N + 15) / 16;   // 16 nodes/block (16 lanes each)
    gather_bf16_kernel<<<gatherBlocks, 256, 0, stream>>>(xb, rowptr, col, inv, m1b, N);

    gather_gemm_kernel<<<(N + 31) / 32, 256, 0, stream>>>(xb, m1b, Wpk, rowptr, col,
                                                          inv, b, out, N);
}